// Round 13
// baseline (173.770 us; speedup 1.0000x reference)
//
#include <hip/hip_runtime.h>
#include <hip/hip_bf16.h>

#define DEVI __device__ __forceinline__

typedef __attribute__((ext_vector_type(8))) short short8;
typedef __attribute__((ext_vector_type(2))) short shortx2;
typedef __attribute__((ext_vector_type(4))) float f32x4;
typedef __attribute__((ext_vector_type(16))) float f32x16;
typedef __attribute__((ext_vector_type(4))) int int4v;

DEVI f32x4 mfma16(short8 a, short8 b, f32x4 c) {
    return __builtin_amdgcn_mfma_f32_16x16x32_bf16(a, b, c, 0, 0, 0);
}
DEVI f32x16 mfma32(short8 a, short8 b, f32x16 c) {
    return __builtin_amdgcn_mfma_f32_32x32x16_bf16(a, b, c, 0, 0, 0);
}

DEVI void gload_lds16(const void* g, void* l) {
    __builtin_amdgcn_global_load_lds(
        (const __attribute__((address_space(1))) void*)g,
        (__attribute__((address_space(3))) void*)l, 16, 0, 0);
}

DEVI float bs2f(short x) {
    union { unsigned u; float f; } uu;
    uu.u = ((unsigned)(unsigned short)x) << 16;
    return uu.f;
}
DEVI short f2bs(float x) {  // RNE
    union { float f; unsigned u; } uu; uu.f = x;
    unsigned r = uu.u + 0x7fffu + ((uu.u >> 16) & 1u);
    return (short)(r >> 16);
}
DEVI int cvtpk_bf16(float lo, float hi) {   // dst.lo = bf16(lo), dst.hi = bf16(hi)
    int r;
    asm("v_cvt_pk_bf16_f32 %0, %1, %2" : "=v"(r) : "v"(lo), "v"(hi));
    return r;
}

// ---------------------------------------------------------------- fused cast f32->bf16 (9 tensors, 1 launch)
struct CastTab {
    const float* src[9];
    short* dst[9];
    int n8[9];
    int blk_off[10];
};

__global__ __launch_bounds__(256) void cast_multi(CastTab tab) {
    int blk = blockIdx.x;
    int seg = 0;
#pragma unroll
    for (int i = 1; i < 9; ++i) seg += (blk >= tab.blk_off[i]);
    int i = (blk - tab.blk_off[seg]) * 256 + threadIdx.x;
    if (i >= tab.n8[seg]) return;
    const f32x4* s4 = (const f32x4*)tab.src[seg];
    f32x4 a = s4[2 * (size_t)i], b = s4[2 * (size_t)i + 1];
    short8 o;
    o[0] = f2bs(a[0]); o[1] = f2bs(a[1]); o[2] = f2bs(a[2]); o[3] = f2bs(a[3]);
    o[4] = f2bs(b[0]); o[5] = f2bs(b[1]); o[6] = f2bs(b[2]); o[7] = f2bs(b[3]);
    *(short8*)(tab.dst[seg] + 8 * (size_t)i) = o;
}

// ---------------------------------------------------------------- grouped 256x256 GEMM (measured-best, frozen)
#define VMWAIT(N) asm volatile("s_waitcnt vmcnt(" #N ")" ::: "memory")

#define PHASE_P(AFC, BFC, AFN, BFN, DBR, KHR, DO_READ, STG, VM)                          \
    {                                                                                    \
        STG;                                                                             \
        const short* lA_ = &lds[DBR][0][KHR][0];                                         \
        const short* lB_ = &lds[DBR][1][KHR][0];                                         \
        __builtin_amdgcn_s_setprio(1);                                                   \
        _Pragma("unroll")                                                                \
        for (int mi = 0; mi < 8; ++mi) {                                                 \
            if (DO_READ)                                                                 \
                AFN[mi] = *(const short8*)&lA_[(wm * 128 + mi * 16 + l15) * 32 + sl8];   \
            _Pragma("unroll")                                                            \
            for (int ni = 0; ni < 4; ++ni)                                               \
                acc[mi][ni] = mfma16(AFC[mi], BFC[ni], acc[mi][ni]);                     \
        }                                                                                \
        if (DO_READ) {                                                                   \
            _Pragma("unroll")                                                            \
            for (int ni = 0; ni < 4; ++ni)                                               \
                BFN[ni] = *(const short8*)&lB_[(wn * 64 + ni * 16 + l15) * 32 + sl8];    \
        }                                                                                \
        __builtin_amdgcn_s_setprio(0);                                                   \
        VM;                                                                              \
        __builtin_amdgcn_sched_barrier(0);                                               \
        __builtin_amdgcn_s_barrier();                                                    \
        __builtin_amdgcn_sched_barrier(0);                                               \
    }

__global__ __launch_bounds__(512, 2) void gemm256_grouped(
    const short* __restrict__ hA, const short* __restrict__ kvA, const short* __restrict__ tA,
    const short* __restrict__ Wqp, const short* __restrict__ Wcat, const short* __restrict__ Wwk,
    const float* __restrict__ bq, const float* __restrict__ bk, const float* __restrict__ bv,
    const float* __restrict__ bwq, const float* __restrict__ bwk,
    short* __restrict__ outq, short* __restrict__ outk, short* __restrict__ outv,
    short* __restrict__ outtq, short* __restrict__ outtk, float SC)
{
    __shared__ __align__(16) short lds[2][2][2][8192];  // [db][A=0/B=1][khalf][256*32]
    const int tid = threadIdx.x;
    const int lane = tid & 63, w8 = tid >> 6;
    const int wm = w8 >> 2, wn = w8 & 3;
    const int l15 = lane & 15, lg = lane >> 4;
    const int sl8 = (lg ^ ((l15 >> 1) & 3)) << 3;   // swizzled fragment slot (shorts)

    // block decode: bijective XCD swizzle (456 = 8*57), then 8-m-tile bands (A band = 4MB = L2)
    const int orig = blockIdx.x;
    const int wg = (orig & 7) * 57 + (orig >> 3);
    int g, m, n;
    if (wg < 64)       { g = 0; int loc = wg;       int band = loc >> 5, r = loc & 31;   m = band * 8 + (r & 7); n = r >> 3; }
    else if (wg < 448) { g = 1; int loc = wg - 64;  int band = loc / 96, r = loc % 96;   m = band * 8 + (r & 7); n = r >> 3; }
    else               { g = 2; int loc = wg - 448; m = loc & 1; n = loc >> 1; }
    const int m0 = m * 256, n0 = n * 256;
    const short* Ap = g == 0 ? hA : (g == 1 ? kvA : tA);
    const short* Wp = g == 0 ? Wqp : (g == 1 ? Wcat : Wwk);

    f32x4 acc[8][4];
#pragma unroll
    for (int i = 0; i < 8; ++i)
#pragma unroll
        for (int j = 0; j < 4; ++j) acc[i][j] = (f32x4){0.f, 0.f, 0.f, 0.f};

    const int Rl0 = w8 * 32 + (lane >> 2);
    const int slot = ((lane & 3) ^ ((lane >> 3) & 3)) * 8;
    const short* pA0 = Ap + (size_t)(m0 + Rl0) * 1024 + slot;
    const short* pA1 = pA0 + (size_t)16 * 1024;
    const short* pB0 = Wp + (size_t)(n0 + Rl0) * 1024 + slot;
    const short* pB1 = pB0 + (size_t)16 * 1024;

    auto stage = [&](int ab, int kh, int tau) {
        short* dst = &lds[tau & 1][ab][kh][w8 * 1024];
        const short* p0 = ab ? pB0 : pA0;
        const short* p1 = ab ? pB1 : pA1;
        int off = tau * 64 + kh * 32;
        gload_lds16(p0 + off, dst);
        gload_lds16(p1 + off, dst + 512);
    };

    short8 af0[8], bf0[4], af1[8], bf1[4];

    stage(0, 0, 0); stage(1, 0, 0);
    stage(0, 1, 0); stage(1, 1, 0);
    stage(0, 0, 1); stage(1, 0, 1);
    stage(0, 1, 1); stage(1, 1, 1);
    VMWAIT(8);
    __builtin_amdgcn_sched_barrier(0);
    __builtin_amdgcn_s_barrier();
    __builtin_amdgcn_sched_barrier(0);
#pragma unroll
    for (int mi = 0; mi < 8; ++mi)
        af0[mi] = *(const short8*)&lds[0][0][0][(wm * 128 + mi * 16 + l15) * 32 + sl8];
#pragma unroll
    for (int ni = 0; ni < 4; ++ni)
        bf0[ni] = *(const short8*)&lds[0][1][0][(wn * 64 + ni * 16 + l15) * 32 + sl8];

    for (int t = 0; t < 14; ++t) {
        const int db = t & 1;
        PHASE_P(af0, bf0, af1, bf1, db, 1, 1,
                { stage(0, 0, t + 2); stage(1, 0, t + 2); }, VMWAIT(8));
        PHASE_P(af1, bf1, af0, bf0, db ^ 1, 0, 1,
                { stage(0, 1, t + 2); stage(1, 1, t + 2); }, VMWAIT(8));
    }
    PHASE_P(af0, bf0, af1, bf1, 0, 1, 1, (void)0, VMWAIT(4));
    PHASE_P(af1, bf1, af0, bf0, 1, 0, 1, (void)0, VMWAIT(0));
    PHASE_P(af0, bf0, af1, bf1, 1, 1, 1, (void)0, (void)0);
    PHASE_P(af1, bf1, af0, bf0, 0, 0, 0, (void)0, (void)0);

    // LDS-transpose epilogue: coalesced 128B-line stores
    short* eps = &lds[0][0][0][0] + (size_t)w8 * 8192;
    const int colbase = n0 + wn * 64;
    const float* bp; short* op; int colw0; float sc;
    if (g == 0)      { bp = bq;  op = outq;  sc = SC;  colw0 = colbase; }
    else if (g == 2) { bp = bwk; op = outtk; sc = 1.f; colw0 = colbase; }
    else {
        int seg = colbase >> 10;
        bp = seg == 0 ? bk : (seg == 1 ? bv : bwq);
        op = seg == 0 ? outk : (seg == 1 ? outv : outtq);
        sc = seg == 2 ? SC : 1.f;
        colw0 = colbase & 1023;
    }
    float bval[4];
#pragma unroll
    for (int ni = 0; ni < 4; ++ni) bval[ni] = bp[colw0 + ni * 16 + l15];

#pragma unroll
    for (int mi = 0; mi < 8; ++mi) {
        int lrow = mi * 16 + lg * 4;
#pragma unroll
        for (int ni = 0; ni < 4; ++ni) {
            int lcol = ni * 16 + l15;
#pragma unroll
            for (int rj = 0; rj < 4; ++rj)
                eps[(lrow + rj) * 64 + lcol] = f2bs((acc[mi][ni][rj] + bval[ni]) * sc);
        }
    }
    asm volatile("" ::: "memory");
    const int erow = lane >> 3, ecol = (lane & 7) * 8;
#pragma unroll
    for (int it = 0; it < 16; ++it) {
        int lrow = it * 8 + erow;
        short8 vv = *(const short8*)&eps[lrow * 64 + ecol];
        *(short8*)&op[(size_t)(m0 + wm * 128 + lrow) * 1024 + colw0 + ecol] = vv;
    }
}

// ---------------------------------------------------------------- 128x128 2-phase GEMM (out-projection, f32 out)
__global__ __launch_bounds__(256) void gemm_bt_f32(
    const short* __restrict__ A, const short* __restrict__ Bt,
    const float* __restrict__ bias, float* __restrict__ Cout, int N, int K)
{
    __shared__ __align__(16) short lA[2][128 * 32];
    __shared__ __align__(16) short lB[2][128 * 32];
    const int tid = threadIdx.x;
    const int lane = tid & 63, w = tid >> 6;
    const int brow = blockIdx.y * 128, bcol = blockIdx.x * 128;
    const int wr = (w >> 1) * 64, wc = (w & 1) * 64;
    const int l15 = lane & 15, lg = lane >> 4;

    f32x4 acc[4][4];
#pragma unroll
    for (int m = 0; m < 4; ++m)
#pragma unroll
        for (int n = 0; n < 4; ++n) acc[m][n] = (f32x4){0.f, 0.f, 0.f, 0.f};

    const short* gA = A + (size_t)brow * K;
    const short* gB = Bt + (size_t)bcol * K;
    const int f0 = (w * 2) * 64 + lane;

    auto stage = [&](int bufi, int k0) {
#pragma unroll
        for (int i = 0; i < 2; ++i) {
            int f = f0 + i * 64;
            int row = f >> 2, kk = (f & 3) * 8;
            gload_lds16(gA + (size_t)row * K + k0 + kk, (void*)(&lA[bufi][(w * 2 + i) * 512]));
            gload_lds16(gB + (size_t)row * K + k0 + kk, (void*)(&lB[bufi][(w * 2 + i) * 512]));
        }
    };

    stage(0, 0);
    __syncthreads();
    int buf = 0;
    for (int k0 = 0; k0 < K; k0 += 32) {
        if (k0 + 32 < K) stage(buf ^ 1, k0 + 32);
        short8 av[4], bv[4];
#pragma unroll
        for (int m = 0; m < 4; ++m)
            av[m] = *(const short8*)&lA[buf][(wr + m * 16 + l15) * 32 + lg * 8];
#pragma unroll
        for (int n = 0; n < 4; ++n)
            bv[n] = *(const short8*)&lB[buf][(wc + n * 16 + l15) * 32 + lg * 8];
#pragma unroll
        for (int m = 0; m < 4; ++m)
#pragma unroll
            for (int n = 0; n < 4; ++n)
                acc[m][n] = mfma16(av[m], bv[n], acc[m][n]);
        __syncthreads();
        buf ^= 1;
    }

#pragma unroll
    for (int n = 0; n < 4; ++n) {
        int col = bcol + wc + n * 16 + l15;
        float bval = bias[col];
#pragma unroll
        for (int m = 0; m < 4; ++m)
#pragma unroll
            for (int r = 0; r < 4; ++r) {
                int row = brow + wr + m * 16 + lg * 4 + r;
                Cout[(size_t)row * N + col] = acc[m][n][r] + bval;
            }
    }
}

// ---------------------------------------------------------------- weights via MFMA
__global__ __launch_bounds__(256) void weights_mfma(
    const short* __restrict__ tq, const short* __restrict__ tk,
    const float* __restrict__ mask, float* __restrict__ wts)
{
    const int S = 1024, TL = 64, D = 1024, HD = 64;
    const int bh = blockIdx.y, b = bh >> 4, h = bh & 15;
    const int tid = threadIdx.x, lane = tid & 63, w = tid >> 6;  // w 0..3
    const int l15 = lane & 15, lg = lane >> 4;
    const int s_base = blockIdx.x * 256 + w * 64;

    short8 bf[4][2];
    const short* tkb = tk + (size_t)b * TL * D + h * HD;
#pragma unroll
    for (int ni = 0; ni < 4; ++ni)
#pragma unroll
        for (int ks = 0; ks < 2; ++ks)
            bf[ni][ks] = *(const short8*)(tkb + (size_t)(ni * 16 + l15) * D + ks * 32 + lg * 8);

    const short* tqb = tq + (size_t)b * S * D + h * HD;
    f32x4 acc[4][4];
#pragma unroll
    for (int i = 0; i < 4; ++i)
#pragma unroll
        for (int j = 0; j < 4; ++j) acc[i][j] = (f32x4){0.f, 0.f, 0.f, 0.f};

#pragma unroll
    for (int mi = 0; mi < 4; ++mi) {
        const short* ap = tqb + (size_t)(s_base + mi * 16 + l15) * D;
        short8 af0 = *(const short8*)(ap + lg * 8);
        short8 af1 = *(const short8*)(ap + 32 + lg * 8);
#pragma unroll
        for (int ni = 0; ni < 4; ++ni) {
            acc[mi][ni] = mfma16(af0, bf[ni][0], acc[mi][ni]);
            acc[mi][ni] = mfma16(af1, bf[ni][1], acc[mi][ni]);
        }
    }

    const float* mb = mask + (size_t)b * S * TL;
    float* wout = wts + (size_t)bh * S;
#pragma unroll
    for (int mi = 0; mi < 4; ++mi) {
        float wsum[4];
#pragma unroll
        for (int rj = 0; rj < 4; ++rj) {
            int s = s_base + mi * 16 + lg * 4 + rj;
            const float* mrow = mb + (size_t)s * TL;
            float ws = 0.f, ms = 0.f;
#pragma unroll
            for (int ni = 0; ni < 4; ++ni) {
                float mv = mrow[ni * 16 + l15];
                ws = fmaf(acc[mi][ni][rj], mv, ws);
                ms += mv;
            }
#pragma unroll
            for (int off = 1; off < 16; off <<= 1) {
                ws += __shfl_xor(ws, off);
                ms += __shfl_xor(ms, off);
            }
            wsum[rj] = (ws / ms) * 1.44269504f;
        }
        if (l15 == 0) {
#pragma unroll
            for (int rj = 0; rj < 4; ++rj)
                wout[s_base + mi * 16 + lg * 4 + rj] = wsum[rj];
        }
    }
}

// ---------------------------------------------------------------- flash attention, swapped-QK, 32x32 MFMA
// 4 waves x 32 q (128-row block, 256 thr), KVBLK=128: 32x32 frags serve 32 q -> K/V LDS bytes
// per q HALVED vs 16x16. mfma32(K,Q): C[col = l31 = q][row(reg,hi) = (reg&3)+8*(reg>>2)+4*hi = s_local]
// -> q fully lane-local (lrun scalar, ONE shfl_xor(32) reduce). PV A-frag: pack regs 8m..8m+7 ->
// element k=16m+8hi+jj holds P at s_local=16m+8(jj>>2)+4hi+(jj&3), so V stored at sigma(s) = s
// with bits 2<->3 swapped reads back as contiguous b128 B-frags. sigma preserves s-pairs (bit0)
// and 64-blocks (bit6).
__global__ __launch_bounds__(256) void flash_kernel(
    const short* __restrict__ q, const short* __restrict__ k, const short* __restrict__ v,
    const float* __restrict__ wts, short* __restrict__ out)
{
    const int T = 512, S = 1024, D = 1024, HD = 64;
    const int bh = blockIdx.x, b = bh >> 4, h = bh & 15;
    const int t0 = blockIdx.y * 128;
    const int tid = threadIdx.x, lane = tid & 63, w = tid >> 6;   // w 0..3
    const int l31 = lane & 31, hi = lane >> 5;

    __shared__ __align__(16) char  lK[2][128 * 128];  // rows XOR-swizzled (byte ^ ((row&7)<<4))
    __shared__ __align__(16) short lV[2][64 * 136];   // [d][sigma(s)], XOR-swizzled by (d>>3)&7

    short8 aq[4];   // Q B-frags: lane col = q = l31, k = ks*16 + hi*8 + j
    {
        const short* qp = q + ((size_t)b * T + t0 + w * 32 + l31) * D + h * HD;
#pragma unroll
        for (int ks = 0; ks < 4; ++ks)
            aq[ks] = *(const short8*)(qp + ks * 16 + hi * 8);
    }

    f32x16 acc[2];
#pragma unroll
    for (int i = 0; i < 2; ++i)
#pragma unroll
        for (int j = 0; j < 16; ++j) acc[i][j] = 0.f;
    float lrun = 0.f;   // per-lane row-sum for q = l31

    const short* kb = k + (size_t)b * S * D + h * HD;
    const short* vb = v + (size_t)b * S * D + h * HD;
    const float* wrow = wts + (size_t)bh * S;

    auto stageK = [&](int bufi, int s0) {
#pragma unroll
        for (int i = 0; i < 4; ++i) {
            int fb = i * 4096 + tid * 16;
            int fb2 = fb ^ (((fb >> 7) & 7) << 4);    // pre-swizzled source, linear LDS dest
            int row = fb2 >> 7, dd = (fb2 & 127) >> 1;
            gload_lds16(kb + (size_t)(s0 + row) * D + dd,
                        (void*)(&lK[bufi][i * 4096 + w * 1024 + (lane << 4)]));
        }
    };
    const int vpair = tid >> 3, vch = tid & 7;   // 32 pairs x 8 d-chunks; 2 halves of 64 s
    auto loadV = [&](int s0, short8* vv) {
        const short* pp = vb + (size_t)(s0 + vpair * 2) * D + vch * 8;
        vv[0] = *(const short8*)pp;
        vv[1] = *(const short8*)(pp + D);
        vv[2] = *(const short8*)(pp + (size_t)64 * D);
        vv[3] = *(const short8*)(pp + (size_t)65 * D);
    };
    auto writeV = [&](int bufi, const short8* vv) {
#pragma unroll
        for (int hlf = 0; hlf < 2; ++hlf) {
            int srow = vpair * 2 + hlf * 64;
            int sig = (srow & ~12) | ((srow & 4) << 1) | ((srow & 8) >> 1);  // swap bits 2,3
#pragma unroll
            for (int j = 0; j < 8; ++j) {
                int d = vch * 8 + j;
                shortx2 pr; pr[0] = vv[hlf * 2][j]; pr[1] = vv[hlf * 2 + 1][j];
                *(shortx2*)&lV[bufi][d * 136 + (sig ^ (((d >> 3) & 7) << 3))] = pr;
            }
        }
    };

    short8 vv[4];
    stageK(0, 0);
    loadV(0, vv);
    writeV(0, vv);
    __syncthreads();
    int buf = 0;

    for (int s0 = 0; s0 < S; s0 += 128) {
        const int nxt = s0 + 128;
        if (nxt < S) { stageK(buf ^ 1, nxt); loadV(nxt, vv); }

        // swapped QK^T (32x32): sc[sb][reg] = P[q=l31][s = s0 + sb*32 + (reg&3)+8*(reg>>2)+4*hi]
        f32x16 sc[4];
        const int swzK = (l31 & 7) << 4;
#pragma unroll
        for (int sb = 0; sb < 4; ++sb) {
            int rbase = (sb * 32 + l31) * 128;
            f32x16 c;
#pragma unroll
            for (int j = 0; j < 16; ++j) c[j] = 0.f;
#pragma unroll
            for (int ks = 0; ks < 4; ++ks) {
                short8 kf = *(const short8*)(&lK[buf][0] + (rbase + ((ks * 32 + hi * 16) ^ swzK)));
                c = mfma32(kf, aq[ks], c);   // A = K (s-rows), B = Q (q-cols)
            }
            sc[sb] = c;
        }

        // weights + no-max softmax, fully per-lane
#pragma unroll
        for (int sb = 0; sb < 4; ++sb) {
#pragma unroll
            for (int kp = 0; kp < 4; ++kp) {
                f32x4 wv4 = *(const f32x4*)&wrow[s0 + sb * 32 + kp * 8 + hi * 4];
#pragma unroll
                for (int c = 0; c < 4; ++c) {
                    float p = exp2f(sc[sb][kp * 4 + c] * wv4[c]);
                    sc[sb][kp * 4 + c] = p; lrun += p;
                }
            }
        }

        if (nxt < S) writeV(buf ^ 1, vv);  // buf^1 retired at last barrier

        // pack + PV per s-block: u[m] elements jj = regs 8m+jj
#pragma unroll
        for (int sb = 0; sb < 4; ++sb) {
            union { int4v i; short8 s; } u0, u1;
            u0.i[0] = cvtpk_bf16(sc[sb][0],  sc[sb][1]);
            u0.i[1] = cvtpk_bf16(sc[sb][2],  sc[sb][3]);
            u0.i[2] = cvtpk_bf16(sc[sb][4],  sc[sb][5]);
            u0.i[3] = cvtpk_bf16(sc[sb][6],  sc[sb][7]);
            u1.i[0] = cvtpk_bf16(sc[sb][8],  sc[sb][9]);
            u1.i[1] = cvtpk_bf16(sc[sb][10], sc[sb][11]);
            u1.i[2] = cvtpk_bf16(sc[sb][12], sc[sb][13]);
            u1.i[3] = cvtpk_bf16(sc[sb][14], sc[sb][15]);
#pragma unroll
            for (int dblk = 0; dblk < 2; ++dblk) {
                int d = dblk * 32 + l31;
                int sw = ((d >> 3) & 7) << 3;
                const short* vrow = &lV[buf][d * 136];
                short8 bv0 = *(const short8*)&vrow[(sb * 32 + hi * 8) ^ sw];
                short8 bv1 = *(const short8*)&vrow[(sb * 32 + 16 + hi * 8) ^ sw];
                acc[dblk] = mfma32(u0.s, bv0, acc[dblk]);
                acc[dblk] = mfma32(u1.s, bv1, acc[dblk]);
            }
        }
        __syncthreads();
        buf ^= 1;
    }

    // finalize: fold hi-halves, gather per-q sums, divide, store
    lrun += __shfl_xor(lrun, 32);
    float rs[16];
#pragma unroll
    for (int reg = 0; reg < 16; ++reg)
        rs[reg] = __shfl(lrun, (reg & 3) + 8 * (reg >> 2) + 4 * hi);

    short* ob = out + ((size_t)b * T + t0 + w * 32) * D + h * HD;
#pragma unroll
    for (int dblk = 0; dblk < 2; ++dblk)
#pragma unroll
        for (int reg = 0; reg < 16; ++reg) {
            int qL = (reg & 3) + 8 * (reg >> 2) + 4 * hi;
            ob[(size_t)qL * D + dblk * 32 + l31] = f2bs(acc[dblk][reg] / rs[reg]);
        }
}

// ---------------------------------------------------------------- launcher
extern "C" void kernel_launch(void* const* d_in, const int* in_sizes, int n_in,
                              void* d_out, int out_size, void* d_ws, size_t ws_size,
                              hipStream_t stream) {
    (void)in_sizes; (void)n_in; (void)out_size; (void)ws_size;
    const int B = 8, T = 512, S = 1024, TL = 64, D = 1024;
    const float SC = 0.125f;  // 64^-0.5

    const float* hidden = (const float*)d_in[0];
    const float* kv     = (const float*)d_in[1];
    const float* target = (const float*)d_in[2];
    const float* mask   = (const float*)d_in[3];
    const float* bq  = (const float*)d_in[5];
    const float* bk  = (const float*)d_in[7];
    const float* bv  = (const float*)d_in[9];
    const float* bwq = (const float*)d_in[11];
    const float* bwk = (const float*)d_in[13];
    const float* bo  = (const float*)d_in[15];

    char* p = (char*)d_ws;
    auto take = [&p](size_t bytes) { char* r = p; p += (bytes + 255) & ~(size_t)255; return r; };
    short* hbf  = (short*)take((size_t)B * T * D * 2);
    short* kvbf = (short*)take((size_t)B * S * D * 2);
    short* tbf  = (short*)take((size_t)B * TL * D * 2);
    short* Wqb  = (short*)take((size_t)D * D * 2);
    short* Wcat = (short*)take((size_t)3 * D * D * 2);   // Wk|Wv|Wwq contiguous
    short* Wwkb = (short*)take((size_t)D * D * 2);
    short* Wob  = (short*)take((size_t)D * D * 2);
    short* qbf  = (short*)take((size_t)B * T * D * 2);
    short* kbf  = (short*)take((size_t)B * S * D * 2);
    short* vbf  = (short*)take((size_t)B * S * D * 2);
    short* tqbf = (short*)take((size_t)B * S * D * 2);
    short* tkbf = (short*)take((size_t)B * TL * D * 2);
    short* aobf = (short*)take((size_t)B * T * D * 2);
    float* wts  = (float*)take((size_t)B * 16 * S * 4);

    CastTab tab;
    const float* srcs[9] = { hidden, kv, target,
                             (const float*)d_in[4], (const float*)d_in[6], (const float*)d_in[8],
                             (const float*)d_in[10], (const float*)d_in[12], (const float*)d_in[14] };
    short* dsts[9] = { hbf, kvbf, tbf, Wqb, Wcat, Wcat + (size_t)D * D, Wcat + (size_t)2 * D * D, Wwkb, Wob };
    size_t ns[9] = { (size_t)B * T * D, (size_t)B * S * D, (size_t)B * TL * D,
                     (size_t)D * D, (size_t)D * D, (size_t)D * D, (size_t)D * D, (size_t)D * D, (size_t)D * D };
    int off = 0;
    for (int i = 0; i < 9; ++i) {
        tab.src[i] = srcs[i]; tab.dst[i] = dsts[i];
        tab.n8[i] = (int)(ns[i] / 8);
        tab.blk_off[i] = off;
        off += (tab.n8[i] + 255) / 256;
    }
    tab.blk_off[9] = off;
    cast_multi<<<dim3(off), dim3(256), 0, stream>>>(tab);

    // all projections in one grouped 256^2 launch (456 blocks)
    gemm256_grouped<<<dim3(456), dim3(512), 0, stream>>>(
        hbf, kvbf, tbf, Wqb, Wcat, Wwkb,
        bq, bk, bv, bwq, bwk,
        qbf, kbf, vbf, tqbf, tkbf, SC);

    weights_mfma<<<dim3(4, B * 16), dim3(256), 0, stream>>>(tqbf, tkbf, mask, wts);
    flash_kernel<<<dim3(B * 16, T / 128), dim3(256), 0, stream>>>(qbf, kbf, vbf, wts, aobf);
    gemm_bt_f32<<<dim3(D / 128, B * T / 128), dim3(256), 0, stream>>>(aobf, Wob, bo, (float*)d_out, D, D);
}

// Round 14
// 162.587 us; speedup vs baseline: 1.0688x; 1.0688x over previous
//
#include <hip/hip_runtime.h>
#include <hip/hip_bf16.h>

#define DEVI __device__ __forceinline__

typedef __attribute__((ext_vector_type(8))) short short8;
typedef __attribute__((ext_vector_type(2))) short shortx2;
typedef __attribute__((ext_vector_type(4))) float f32x4;
typedef __attribute__((ext_vector_type(4))) int int4v;

DEVI f32x4 mfma16(short8 a, short8 b, f32x4 c) {
    return __builtin_amdgcn_mfma_f32_16x16x32_bf16(a, b, c, 0, 0, 0);
}

DEVI void gload_lds16(const void* g, void* l) {
    __builtin_amdgcn_global_load_lds(
        (const __attribute__((address_space(1))) void*)g,
        (__attribute__((address_space(3))) void*)l, 16, 0, 0);
}

DEVI float bs2f(short x) {
    union { unsigned u; float f; } uu;
    uu.u = ((unsigned)(unsigned short)x) << 16;
    return uu.f;
}
DEVI short f2bs(float x) {  // RNE
    union { float f; unsigned u; } uu; uu.f = x;
    unsigned r = uu.u + 0x7fffu + ((uu.u >> 16) & 1u);
    return (short)(r >> 16);
}
DEVI int cvtpk_bf16(float lo, float hi) {   // dst.lo = bf16(lo), dst.hi = bf16(hi)
    int r;
    asm("v_cvt_pk_bf16_f32 %0, %1, %2" : "=v"(r) : "v"(lo), "v"(hi));
    return r;
}

// ---------------------------------------------------------------- fused cast f32->bf16 (9 tensors, 1 launch)
struct CastTab {
    const float* src[9];
    short* dst[9];
    int n8[9];
    int blk_off[10];
};

__global__ __launch_bounds__(256) void cast_multi(CastTab tab) {
    int blk = blockIdx.x;
    int seg = 0;
#pragma unroll
    for (int i = 1; i < 9; ++i) seg += (blk >= tab.blk_off[i]);
    int i = (blk - tab.blk_off[seg]) * 256 + threadIdx.x;
    if (i >= tab.n8[seg]) return;
    const f32x4* s4 = (const f32x4*)tab.src[seg];
    f32x4 a = s4[2 * (size_t)i], b = s4[2 * (size_t)i + 1];
    short8 o;
    o[0] = f2bs(a[0]); o[1] = f2bs(a[1]); o[2] = f2bs(a[2]); o[3] = f2bs(a[3]);
    o[4] = f2bs(b[0]); o[5] = f2bs(b[1]); o[6] = f2bs(b[2]); o[7] = f2bs(b[3]);
    *(short8*)(tab.dst[seg] + 8 * (size_t)i) = o;
}

// ---------------------------------------------------------------- grouped 256x256 GEMM (measured-best, frozen)
#define VMWAIT(N) asm volatile("s_waitcnt vmcnt(" #N ")" ::: "memory")

#define PHASE_P(AFC, BFC, AFN, BFN, DBR, KHR, DO_READ, STG, VM)                          \
    {                                                                                    \
        STG;                                                                             \
        const short* lA_ = &lds[DBR][0][KHR][0];                                         \
        const short* lB_ = &lds[DBR][1][KHR][0];                                         \
        __builtin_amdgcn_s_setprio(1);                                                   \
        _Pragma("unroll")                                                                \
        for (int mi = 0; mi < 8; ++mi) {                                                 \
            if (DO_READ)                                                                 \
                AFN[mi] = *(const short8*)&lA_[(wm * 128 + mi * 16 + l15) * 32 + sl8];   \
            _Pragma("unroll")                                                            \
            for (int ni = 0; ni < 4; ++ni)                                               \
                acc[mi][ni] = mfma16(AFC[mi], BFC[ni], acc[mi][ni]);                     \
        }                                                                                \
        if (DO_READ) {                                                                   \
            _Pragma("unroll")                                                            \
            for (int ni = 0; ni < 4; ++ni)                                               \
                BFN[ni] = *(const short8*)&lB_[(wn * 64 + ni * 16 + l15) * 32 + sl8];    \
        }                                                                                \
        __builtin_amdgcn_s_setprio(0);                                                   \
        VM;                                                                              \
        __builtin_amdgcn_sched_barrier(0);                                               \
        __builtin_amdgcn_s_barrier();                                                    \
        __builtin_amdgcn_sched_barrier(0);                                               \
    }

__global__ __launch_bounds__(512, 2) void gemm256_grouped(
    const short* __restrict__ hA, const short* __restrict__ kvA, const short* __restrict__ tA,
    const short* __restrict__ Wqp, const short* __restrict__ Wcat, const short* __restrict__ Wwk,
    const float* __restrict__ bq, const float* __restrict__ bk, const float* __restrict__ bv,
    const float* __restrict__ bwq, const float* __restrict__ bwk,
    short* __restrict__ outq, short* __restrict__ outk, short* __restrict__ outv,
    short* __restrict__ outtq, short* __restrict__ outtk, float SC)
{
    __shared__ __align__(16) short lds[2][2][2][8192];  // [db][A=0/B=1][khalf][256*32]
    const int tid = threadIdx.x;
    const int lane = tid & 63, w8 = tid >> 6;
    const int wm = w8 >> 2, wn = w8 & 3;
    const int l15 = lane & 15, lg = lane >> 4;
    const int sl8 = (lg ^ ((l15 >> 1) & 3)) << 3;   // swizzled fragment slot (shorts)

    // block decode: bijective XCD swizzle (456 = 8*57), then 8-m-tile bands (A band = 4MB = L2)
    const int orig = blockIdx.x;
    const int wg = (orig & 7) * 57 + (orig >> 3);
    int g, m, n;
    if (wg < 64)       { g = 0; int loc = wg;       int band = loc >> 5, r = loc & 31;   m = band * 8 + (r & 7); n = r >> 3; }
    else if (wg < 448) { g = 1; int loc = wg - 64;  int band = loc / 96, r = loc % 96;   m = band * 8 + (r & 7); n = r >> 3; }
    else               { g = 2; int loc = wg - 448; m = loc & 1; n = loc >> 1; }
    const int m0 = m * 256, n0 = n * 256;
    const short* Ap = g == 0 ? hA : (g == 1 ? kvA : tA);
    const short* Wp = g == 0 ? Wqp : (g == 1 ? Wcat : Wwk);

    f32x4 acc[8][4];
#pragma unroll
    for (int i = 0; i < 8; ++i)
#pragma unroll
        for (int j = 0; j < 4; ++j) acc[i][j] = (f32x4){0.f, 0.f, 0.f, 0.f};

    const int Rl0 = w8 * 32 + (lane >> 2);
    const int slot = ((lane & 3) ^ ((lane >> 3) & 3)) * 8;
    const short* pA0 = Ap + (size_t)(m0 + Rl0) * 1024 + slot;
    const short* pA1 = pA0 + (size_t)16 * 1024;
    const short* pB0 = Wp + (size_t)(n0 + Rl0) * 1024 + slot;
    const short* pB1 = pB0 + (size_t)16 * 1024;

    auto stage = [&](int ab, int kh, int tau) {
        short* dst = &lds[tau & 1][ab][kh][w8 * 1024];
        const short* p0 = ab ? pB0 : pA0;
        const short* p1 = ab ? pB1 : pA1;
        int off = tau * 64 + kh * 32;
        gload_lds16(p0 + off, dst);
        gload_lds16(p1 + off, dst + 512);
    };

    short8 af0[8], bf0[4], af1[8], bf1[4];

    stage(0, 0, 0); stage(1, 0, 0);
    stage(0, 1, 0); stage(1, 1, 0);
    stage(0, 0, 1); stage(1, 0, 1);
    stage(0, 1, 1); stage(1, 1, 1);
    VMWAIT(8);
    __builtin_amdgcn_sched_barrier(0);
    __builtin_amdgcn_s_barrier();
    __builtin_amdgcn_sched_barrier(0);
#pragma unroll
    for (int mi = 0; mi < 8; ++mi)
        af0[mi] = *(const short8*)&lds[0][0][0][(wm * 128 + mi * 16 + l15) * 32 + sl8];
#pragma unroll
    for (int ni = 0; ni < 4; ++ni)
        bf0[ni] = *(const short8*)&lds[0][1][0][(wn * 64 + ni * 16 + l15) * 32 + sl8];

    for (int t = 0; t < 14; ++t) {
        const int db = t & 1;
        PHASE_P(af0, bf0, af1, bf1, db, 1, 1,
                { stage(0, 0, t + 2); stage(1, 0, t + 2); }, VMWAIT(8));
        PHASE_P(af1, bf1, af0, bf0, db ^ 1, 0, 1,
                { stage(0, 1, t + 2); stage(1, 1, t + 2); }, VMWAIT(8));
    }
    PHASE_P(af0, bf0, af1, bf1, 0, 1, 1, (void)0, VMWAIT(4));
    PHASE_P(af1, bf1, af0, bf0, 1, 0, 1, (void)0, VMWAIT(0));
    PHASE_P(af0, bf0, af1, bf1, 1, 1, 1, (void)0, (void)0);
    PHASE_P(af1, bf1, af0, bf0, 0, 0, 0, (void)0, (void)0);

    // LDS-transpose epilogue: coalesced 128B-line stores
    short* eps = &lds[0][0][0][0] + (size_t)w8 * 8192;
    const int colbase = n0 + wn * 64;
    const float* bp; short* op; int colw0; float sc;
    if (g == 0)      { bp = bq;  op = outq;  sc = SC;  colw0 = colbase; }
    else if (g == 2) { bp = bwk; op = outtk; sc = 1.f; colw0 = colbase; }
    else {
        int seg = colbase >> 10;
        bp = seg == 0 ? bk : (seg == 1 ? bv : bwq);
        op = seg == 0 ? outk : (seg == 1 ? outv : outtq);
        sc = seg == 2 ? SC : 1.f;
        colw0 = colbase & 1023;
    }
    float bval[4];
#pragma unroll
    for (int ni = 0; ni < 4; ++ni) bval[ni] = bp[colw0 + ni * 16 + l15];

#pragma unroll
    for (int mi = 0; mi < 8; ++mi) {
        int lrow = mi * 16 + lg * 4;
#pragma unroll
        for (int ni = 0; ni < 4; ++ni) {
            int lcol = ni * 16 + l15;
#pragma unroll
            for (int rj = 0; rj < 4; ++rj)
                eps[(lrow + rj) * 64 + lcol] = f2bs((acc[mi][ni][rj] + bval[ni]) * sc);
        }
    }
    asm volatile("" ::: "memory");
    const int erow = lane >> 3, ecol = (lane & 7) * 8;
#pragma unroll
    for (int it = 0; it < 16; ++it) {
        int lrow = it * 8 + erow;
        short8 vv = *(const short8*)&eps[lrow * 64 + ecol];
        *(short8*)&op[(size_t)(m0 + wm * 128 + lrow) * 1024 + colw0 + ecol] = vv;
    }
}

// ---------------------------------------------------------------- out-projection: 128x64 2-phase, f32 out
// M=4096, N=1024, K=1024. 512 blocks (2/CU -> 8 waves/CU + cross-block overlap; fixes the old
// 256-block/1-wave-per-SIMD config). Bijective XCD swizzle (512 = 8*64): same-m blocks share the
// A panel in one XCD L2. Slot swizzle identical to gemm256 (R6-proven): physical slot p&3 holds
// logical (p&3)^((row>>1)&3); fragment reads use sl8 = (lg ^ ((l15>>1)&3))<<3 -> 2-way banks.
__global__ __launch_bounds__(256) void gemm_out_f32(
    const short* __restrict__ A, const short* __restrict__ Bt,
    const float* __restrict__ bias, float* __restrict__ Cout)
{
    const int K = 1024, N = 1024;
    __shared__ __align__(16) short lA[2][4096];   // 128 rows x 32 shorts
    __shared__ __align__(16) short lB[2][2048];   // 64 rows x 32 shorts
    const int tid = threadIdx.x;
    const int lane = tid & 63, w = tid >> 6;
    const int wr = (w >> 1) * 64, wc = (w & 1) * 32;
    const int l15 = lane & 15, lg = lane >> 4;
    const int sl8 = (lg ^ ((l15 >> 1) & 3)) << 3;

    const int wg = (blockIdx.x & 7) * 64 + (blockIdx.x >> 3);   // bijective, 512 = 8*64
    const int brow = (wg >> 4) * 128, bcol = (wg & 15) * 64;

    f32x4 acc[4][2];
#pragma unroll
    for (int m = 0; m < 4; ++m)
#pragma unroll
        for (int n = 0; n < 2; ++n) acc[m][n] = (f32x4){0.f, 0.f, 0.f, 0.f};

    const int rowc = tid >> 2;                                  // chunk row 0..63
    const int sg = ((tid & 3) ^ ((tid >> 3) & 3)) * 8;          // logical source slot
    const short* pA0 = A + (size_t)(brow + rowc) * K + sg;
    const short* pA1 = pA0 + (size_t)64 * K;
    const short* pB  = Bt + (size_t)(bcol + rowc) * K + sg;

    auto stage = [&](int bufi, int k0) {
        gload_lds16(pA0 + k0, (void*)(&lA[bufi][tid * 8]));
        gload_lds16(pA1 + k0, (void*)(&lA[bufi][tid * 8 + 2048]));
        gload_lds16(pB + k0,  (void*)(&lB[bufi][tid * 8]));
    };

    stage(0, 0);
    __syncthreads();
    int buf = 0;
    for (int k0 = 0; k0 < K; k0 += 32) {
        if (k0 + 32 < K) stage(buf ^ 1, k0 + 32);
        short8 av[4], bv[2];
#pragma unroll
        for (int m = 0; m < 4; ++m)
            av[m] = *(const short8*)&lA[buf][(wr + m * 16 + l15) * 32 + sl8];
#pragma unroll
        for (int n = 0; n < 2; ++n)
            bv[n] = *(const short8*)&lB[buf][(wc + n * 16 + l15) * 32 + sl8];
#pragma unroll
        for (int m = 0; m < 4; ++m)
#pragma unroll
            for (int n = 0; n < 2; ++n)
                acc[m][n] = mfma16(av[m], bv[n], acc[m][n]);
        __syncthreads();
        buf ^= 1;
    }

#pragma unroll
    for (int n = 0; n < 2; ++n) {
        int col = bcol + wc + n * 16 + l15;
        float bval = bias[col];
#pragma unroll
        for (int m = 0; m < 4; ++m)
#pragma unroll
            for (int r = 0; r < 4; ++r) {
                int row = brow + wr + m * 16 + lg * 4 + r;
                Cout[(size_t)row * N + col] = acc[m][n][r] + bval;
            }
    }
}

// ---------------------------------------------------------------- weights via MFMA
__global__ __launch_bounds__(256) void weights_mfma(
    const short* __restrict__ tq, const short* __restrict__ tk,
    const float* __restrict__ mask, float* __restrict__ wts)
{
    const int S = 1024, TL = 64, D = 1024, HD = 64;
    const int bh = blockIdx.y, b = bh >> 4, h = bh & 15;
    const int tid = threadIdx.x, lane = tid & 63, w = tid >> 6;  // w 0..3
    const int l15 = lane & 15, lg = lane >> 4;
    const int s_base = blockIdx.x * 256 + w * 64;

    short8 bf[4][2];
    const short* tkb = tk + (size_t)b * TL * D + h * HD;
#pragma unroll
    for (int ni = 0; ni < 4; ++ni)
#pragma unroll
        for (int ks = 0; ks < 2; ++ks)
            bf[ni][ks] = *(const short8*)(tkb + (size_t)(ni * 16 + l15) * D + ks * 32 + lg * 8);

    const short* tqb = tq + (size_t)b * S * D + h * HD;
    f32x4 acc[4][4];
#pragma unroll
    for (int i = 0; i < 4; ++i)
#pragma unroll
        for (int j = 0; j < 4; ++j) acc[i][j] = (f32x4){0.f, 0.f, 0.f, 0.f};

#pragma unroll
    for (int mi = 0; mi < 4; ++mi) {
        const short* ap = tqb + (size_t)(s_base + mi * 16 + l15) * D;
        short8 af0 = *(const short8*)(ap + lg * 8);
        short8 af1 = *(const short8*)(ap + 32 + lg * 8);
#pragma unroll
        for (int ni = 0; ni < 4; ++ni) {
            acc[mi][ni] = mfma16(af0, bf[ni][0], acc[mi][ni]);
            acc[mi][ni] = mfma16(af1, bf[ni][1], acc[mi][ni]);
        }
    }

    const float* mb = mask + (size_t)b * S * TL;
    float* wout = wts + (size_t)bh * S;
#pragma unroll
    for (int mi = 0; mi < 4; ++mi) {
        float wsum[4];
#pragma unroll
        for (int rj = 0; rj < 4; ++rj) {
            int s = s_base + mi * 16 + lg * 4 + rj;
            const float* mrow = mb + (size_t)s * TL;
            float ws = 0.f, ms = 0.f;
#pragma unroll
            for (int ni = 0; ni < 4; ++ni) {
                float mv = mrow[ni * 16 + l15];
                ws = fmaf(acc[mi][ni][rj], mv, ws);
                ms += mv;
            }
#pragma unroll
            for (int off = 1; off < 16; off <<= 1) {
                ws += __shfl_xor(ws, off);
                ms += __shfl_xor(ms, off);
            }
            wsum[rj] = (ws / ms) * 1.44269504f;
        }
        if (l15 == 0) {
#pragma unroll
            for (int rj = 0; rj < 4; ++rj)
                wout[s_base + mi * 16 + lg * 4 + rj] = wsum[rj];
        }
    }
}

// ---------------------------------------------------------------- flash attention, swapped-QK, KVBLK=128
// (R12 measured-best config: 8 waves x 16 q-rows, 512 thr, 16x16 MFMA.)
// mfma(K,Q): sc8[n][r] = P[q = w*16 + l15][s = s0 + n*16 + lg*4 + r], n = 0..7.
// V stored s-permuted sigma(s) = [s6 s5 | s3 s2 | s4 | s1 s0] so the lane's 32 P-values (packed
// via v_cvt_pk_bf16_f32 into u0..u3) form valid PV A-fragments; V read as clean b128.
__global__ __launch_bounds__(512) void flash_kernel(
    const short* __restrict__ q, const short* __restrict__ k, const short* __restrict__ v,
    const float* __restrict__ wts, short* __restrict__ out)
{
    const int T = 512, S = 1024, D = 1024, HD = 64;
    const int bh = blockIdx.x, b = bh >> 4, h = bh & 15;
    const int t0 = blockIdx.y * 128;
    const int tid = threadIdx.x, lane = tid & 63, w = tid >> 6;   // w 0..7
    const int l15 = lane & 15, lg = lane >> 4;

    __shared__ __align__(16) char  lK[2][128 * 128];  // rows XOR-swizzled (byte ^ ((row&7)<<4))
    __shared__ __align__(16) short lV[2][64 * 136];   // [d][sigma(s)], XOR-swizzled by (d>>3)&7

    short8 aq[2];   // Q fragment (B-operand): lane l15 = q-row, lg = d-slot
    {
        const short* qp = q + ((size_t)b * T + t0 + w * 16 + l15) * D + h * HD;
        aq[0] = *(const short8*)(qp + lg * 8);
        aq[1] = *(const short8*)(qp + 32 + lg * 8);
    }

    f32x4 acc[4];
#pragma unroll
    for (int n = 0; n < 4; ++n) acc[n] = (f32x4){0.f, 0.f, 0.f, 0.f};
    float lrun = 0.f;   // per-lane partial row-sum for q = l15

    const short* kb = k + (size_t)b * S * D + h * HD;
    const short* vb = v + (size_t)b * S * D + h * HD;
    const float* wrow = wts + (size_t)bh * S;

    auto stageK = [&](int bufi, int s0) {
#pragma unroll
        for (int i = 0; i < 2; ++i) {
            int fb = i * 8192 + (w * 64 + lane) * 16;
            int fb2 = fb ^ (((fb >> 7) & 7) << 4);    // pre-swizzled source, linear LDS dest
            int row = fb2 >> 7, dd = (fb2 & 127) >> 1;
            gload_lds16(kb + (size_t)(s0 + row) * D + dd,
                        (void*)(&lK[bufi][i * 8192 + w * 1024]));
        }
    };
    const int vpair = tid >> 3, vch = tid & 7;        // all 512 threads: s-row pair + d-chunk
    auto loadV = [&](int s0, short8& a, short8& b2) {
        const short* pp = vb + (size_t)(s0 + vpair * 2) * D + vch * 8;
        a  = *(const short8*)pp;
        b2 = *(const short8*)(pp + D);
    };
    auto writeV = [&](int bufi, const short8& a, const short8& b2) {
        int srow = vpair * 2;
        int sig = ((srow >> 5) << 5) | (((srow >> 2) & 3) << 3)
                | (((srow >> 4) & 1) << 2) | (srow & 3);     // sigma(s); sigma(s+1)=sigma(s)+1
#pragma unroll
        for (int j = 0; j < 8; ++j) {
            int d = vch * 8 + j;
            shortx2 pr; pr[0] = a[j]; pr[1] = b2[j];
            *(shortx2*)&lV[bufi][d * 136 + (sig ^ (((d >> 3) & 7) << 3))] = pr;
        }
    };

    short8 va, vb2;
    stageK(0, 0);
    loadV(0, va, vb2);
    writeV(0, va, vb2);
    __syncthreads();
    int buf = 0;

    for (int s0 = 0; s0 < S; s0 += 128) {
        const int nxt = s0 + 128;
        if (nxt < S) { stageK(buf ^ 1, nxt); loadV(nxt, va, vb2); }

        // swapped QK^T: sc8[n][r] = P[q = l15][s = s0 + n*16 + lg*4 + r]
        f32x4 sc8[8];
#pragma unroll
        for (int n = 0; n < 8; ++n) {
            int r = n * 16 + l15;
            int swz = (r & 7) << 4;
            int base = r * 128 + lg * 16;
            short8 kf0 = *(const short8*)(&lK[buf][0] + (base ^ swz));
            short8 kf1 = *(const short8*)(&lK[buf][0] + ((base + 64) ^ swz));
            f32x4 c = (f32x4){0.f, 0.f, 0.f, 0.f};
            c = mfma16(kf0, aq[0], c);   // A = K (s-rows), B = Q (q-cols)
            c = mfma16(kf1, aq[1], c);
            sc8[n] = c;
        }

        // weights (aligned f32x4 per n) + no-max softmax, fully per-lane
#pragma unroll
        for (int n = 0; n < 8; ++n) {
            f32x4 wv4 = *(const f32x4*)&wrow[s0 + n * 16 + lg * 4];  // pre-scaled by log2e
#pragma unroll
            for (int r = 0; r < 4; ++r) {
                float p = exp2f(sc8[n][r] * wv4[r]);
                sc8[n][r] = p; lrun += p;
            }
        }

        if (nxt < S) writeV(buf ^ 1, va, vb2);  // buf^1 retired at last barrier

        // pack P into PV A-fragments (u[ks] covers kappa = ks*32 + lg*8 + c)
        union { int4v i; short8 s; } u0, u1, u2, u3;
        u0.i[0] = cvtpk_bf16(sc8[0][0], sc8[0][1]);
        u0.i[1] = cvtpk_bf16(sc8[0][2], sc8[0][3]);
        u0.i[2] = cvtpk_bf16(sc8[1][0], sc8[1][1]);
        u0.i[3] = cvtpk_bf16(sc8[1][2], sc8[1][3]);
        u1.i[0] = cvtpk_bf16(sc8[2][0], sc8[2][1]);
        u1.i[1] = cvtpk_bf16(sc8[2][2], sc8[2][3]);
        u1.i[2] = cvtpk_bf16(sc8[3][0], sc8[3][1]);
        u1.i[3] = cvtpk_bf16(sc8[3][2], sc8[3][3]);
        u2.i[0] = cvtpk_bf16(sc8[4][0], sc8[4][1]);
        u2.i[1] = cvtpk_bf16(sc8[4][2], sc8[4][3]);
        u2.i[2] = cvtpk_bf16(sc8[5][0], sc8[5][1]);
        u2.i[3] = cvtpk_bf16(sc8[5][2], sc8[5][3]);
        u3.i[0] = cvtpk_bf16(sc8[6][0], sc8[6][1]);
        u3.i[1] = cvtpk_bf16(sc8[6][2], sc8[6][3]);
        u3.i[2] = cvtpk_bf16(sc8[7][0], sc8[7][1]);
        u3.i[3] = cvtpk_bf16(sc8[7][2], sc8[7][3]);

        // PV: A = P (q rows, k = permuted s), B = V[sigma] (d cols)
#pragma unroll
        for (int n2 = 0; n2 < 4; ++n2) {
            int d = n2 * 16 + l15;
            int sw = ((d >> 3) & 7) << 3;
            const short* vrow = &lV[buf][d * 136];
            short8 bv0 = *(const short8*)&vrow[(lg * 8) ^ sw];
            short8 bv1 = *(const short8*)&vrow[(32 + lg * 8) ^ sw];
            short8 bv2 = *(const short8*)&vrow[(64 + lg * 8) ^ sw];
            short8 bv3 = *(const short8*)&vrow[(96 + lg * 8) ^ sw];
            acc[n2] = mfma16(u0.s, bv0, acc[n2]);
            acc[n2] = mfma16(u1.s, bv1, acc[n2]);
            acc[n2] = mfma16(u2.s, bv2, acc[n2]);
            acc[n2] = mfma16(u3.s, bv3, acc[n2]);
        }
        __syncthreads();
        buf ^= 1;
    }

    // row-sum finalize: reduce over lg lanes, then gather per output row q = lg*4 + r
    lrun += __shfl_xor(lrun, 16);
    lrun += __shfl_xor(lrun, 32);
    float rsum[4];
#pragma unroll
    for (int r = 0; r < 4; ++r) rsum[r] = __shfl(lrun, lg * 4 + r);

    short* ob = out + ((size_t)b * T + t0 + w * 16) * D + h * HD;
#pragma unroll
    for (int n2 = 0; n2 < 4; ++n2)
#pragma unroll
        for (int r = 0; r < 4; ++r)
            ob[(size_t)(lg * 4 + r) * D + n2 * 16 + l15] = f2bs(acc[n2][r] / rsum[r]);
}

// ---------------------------------------------------------------- launcher
extern "C" void kernel_launch(void* const* d_in, const int* in_sizes, int n_in,
                              void* d_out, int out_size, void* d_ws, size_t ws_size,
                              hipStream_t stream) {
    (void)in_sizes; (void)n_in; (void)out_size; (void)ws_size;
    const int B = 8, T = 512, S = 1024, TL = 64, D = 1024;
    const float SC = 0.125f;  // 64^-0.5

    const float* hidden = (const float*)d_in[0];
    const float* kv     = (const float*)d_in[1];
    const float* target = (const float*)d_in[2];
    const float* mask   = (const float*)d_in[3];
    const float* bq  = (const float*)d_in[5];
    const float* bk  = (const float*)d_in[7];
    const float* bv  = (const float*)d_in[9];
    const float* bwq = (const float*)d_in[11];
    const float* bwk = (const float*)d_in[13];
    const float* bo  = (const float*)d_in[15];

    char* p = (char*)d_ws;
    auto take = [&p](size_t bytes) { char* r = p; p += (bytes + 255) & ~(size_t)255; return r; };
    short* hbf  = (short*)take((size_t)B * T * D * 2);
    short* kvbf = (short*)take((size_t)B * S * D * 2);
    short* tbf  = (short*)take((size_t)B * TL * D * 2);
    short* Wqb  = (short*)take((size_t)D * D * 2);
    short* Wcat = (short*)take((size_t)3 * D * D * 2);   // Wk|Wv|Wwq contiguous
    short* Wwkb = (short*)take((size_t)D * D * 2);
    short* Wob  = (short*)take((size_t)D * D * 2);
    short* qbf  = (short*)take((size_t)B * T * D * 2);
    short* kbf  = (short*)take((size_t)B * S * D * 2);
    short* vbf  = (short*)take((size_t)B * S * D * 2);
    short* tqbf = (short*)take((size_t)B * S * D * 2);
    short* tkbf = (short*)take((size_t)B * TL * D * 2);
    short* aobf = (short*)take((size_t)B * T * D * 2);
    float* wts  = (float*)take((size_t)B * 16 * S * 4);

    CastTab tab;
    const float* srcs[9] = { hidden, kv, target,
                             (const float*)d_in[4], (const float*)d_in[6], (const float*)d_in[8],
                             (const float*)d_in[10], (const float*)d_in[12], (const float*)d_in[14] };
    short* dsts[9] = { hbf, kvbf, tbf, Wqb, Wcat, Wcat + (size_t)D * D, Wcat + (size_t)2 * D * D, Wwkb, Wob };
    size_t ns[9] = { (size_t)B * T * D, (size_t)B * S * D, (size_t)B * TL * D,
                     (size_t)D * D, (size_t)D * D, (size_t)D * D, (size_t)D * D, (size_t)D * D, (size_t)D * D };
    int off = 0;
    for (int i = 0; i < 9; ++i) {
        tab.src[i] = srcs[i]; tab.dst[i] = dsts[i];
        tab.n8[i] = (int)(ns[i] / 8);
        tab.blk_off[i] = off;
        off += (tab.n8[i] + 255) / 256;
    }
    tab.blk_off[9] = off;
    cast_multi<<<dim3(off), dim3(256), 0, stream>>>(tab);

    // all projections in one grouped 256^2 launch (456 blocks)
    gemm256_grouped<<<dim3(456), dim3(512), 0, stream>>>(
        hbf, kvbf, tbf, Wqb, Wcat, Wwkb,
        bq, bk, bv, bwq, bwk,
        qbf, kbf, vbf, tqbf, tkbf, SC);

    weights_mfma<<<dim3(4, B * 16), dim3(256), 0, stream>>>(tqbf, tkbf, mask, wts);
    flash_kernel<<<dim3(B * 16, T / 128), dim3(512), 0, stream>>>(qbf, kbf, vbf, wts, aobf);
    gemm_out_f32<<<dim3(512), dim3(256), 0, stream>>>(aobf, Wob, bo, (float*)d_out);
}